// Round 7
// baseline (445.103 us; speedup 1.0000x reference)
//
#include <hip/hip_runtime.h>
#include <math.h>

#define BN_EPS 1e-3f

static constexpr float CR0 = -3.14159265f;
static constexpr float CR1 = -2.0f;
static constexpr float CVS0 = (float)((3.14159265 * 2.0) / 512.0);
static constexpr float CVS1 = (float)(6.0 / 48.0);
#define BEV_SXY (220 * 250)
#define BEV_SY 250

typedef __attribute__((ext_vector_type(8))) __bf16 bf16x8_t;
typedef __attribute__((ext_vector_type(4))) float f32x4_t;

union ABu { uint4 q; unsigned short us[8]; bf16x8_t bf; };

__device__ __forceinline__ float bnr(float x, float a, float b) {
    float v = fmaf(x, a, b);
    return v > 0.f ? v : 0.f;
}
__device__ __forceinline__ float bf2f(unsigned short u) {
    return __uint_as_float(((unsigned)u) << 16);
}
__device__ __forceinline__ unsigned short f2bf(float f) {
    unsigned u = __float_as_uint(f);
    u += 0x7FFFu + ((u >> 16) & 1u);
    return (unsigned short)(u >> 16);
}
// BN coefs from 8-way replicated stats: stR[r*2C + ch] = sum, stR[r*2C + C + ch] = sumsq
__device__ __forceinline__ void bn_ab8(const float* stR, const float* g, const float* b,
                                       int C, int ch, float invn, float& a, float& bb) {
    float sm = 0.f, sq = 0.f;
#pragma unroll
    for (int r = 0; r < 8; r++) {
        sm += stR[r * 2 * C + ch];
        sq += stR[r * 2 * C + C + ch];
    }
    float m = sm * invn;
    float var = sq * invn - m * m;
    a = g[ch] * rsqrtf(var + BN_EPS);
    bb = b[ch] - m * a;
}

// order-preserving float->u32 key (key==0 reserved as "empty": only -NaN maps there)
__device__ __forceinline__ unsigned fkey(float f) {
    unsigned u = __float_as_uint(f);
    return (u & 0x80000000u) ? ~u : (u | 0x80000000u);
}
__device__ __forceinline__ float dec_key(unsigned k, float a, float b) {
    if (k == 0u) return 0.f;
    unsigned u = (k & 0x80000000u) ? (k ^ 0x80000000u) : ~k;
    float v = fmaf(__uint_as_float(u), a, b);
    return v > 0.f ? v : 0.f;
}

// ---- segment sums (u64 fixed-point packed atomics) + conv-weight pre-pack ----
__global__ void k_scatter_sums(const float* __restrict__ pts, const float* __restrict__ pcyl,
                               const int* __restrict__ binv, const int* __restrict__ cinv,
                               const float* __restrict__ wc, unsigned short* __restrict__ wctb,
                               unsigned long long* __restrict__ bacc,
                               unsigned long long* __restrict__ cacc,
                               int N, int Nb, int Nc) {
    int p = blockIdx.x * blockDim.x + threadIdx.x;
    if (p < 9 * 4096) {
        int j = p & 7, oc = (p >> 3) & 63, quad = (p >> 9) & 3, kc = (p >> 11) & 1, tap = p >> 12;
        int ic = kc * 32 + quad * 8 + j;
        wctb[p] = f2bf(wc[((oc * 64 + ic) * 3 + tap / 3) * 3 + tap % 3]);
    }
    if (p >= N) return;
    float x = pts[p * 5 + 1], y = pts[p * 5 + 2];
    float ph = pcyl[p * 3 + 0], z = pcyl[p * 3 + 1];
    int bi = binv[p], ci = cinv[p];
    unsigned long long xa = (1ull << 44) + (unsigned long long)(x * 1048576.0f + 0.5f);
    unsigned long long ya = (unsigned long long)((y + 40.0f) * 16777216.0f + 0.5f);
    unsigned long long pa = (1ull << 44) + (unsigned long long)((ph + 3.14159265f) * 16777216.0f + 0.5f);
    unsigned long long za = (unsigned long long)((z + 3.0f) * 16777216.0f + 0.5f);
    atomicAdd(&bacc[2 * (long)bi], xa);
    atomicAdd(&bacc[2 * (long)bi + 1], ya);
    atomicAdd(&cacc[2 * (long)ci], pa);
    atomicAdd(&cacc[2 * (long)ci + 1], za);
}

// ---- 16-feat build + GEMM1 (16->64), h1 row-major bf16 via LDS transpose ----
// st1 fused: per-block LDS reduce -> 128 atomics into replica (blockIdx&7).
__global__ __launch_bounds__(256) void k_feat_gemm1(const float* __restrict__ pts,
        const float* __restrict__ pcyl, const float* __restrict__ cylidx,
        const float* __restrict__ bevidx, const int* __restrict__ binv,
        const int* __restrict__ cinv, const unsigned long long* __restrict__ bacc,
        const unsigned long long* __restrict__ cacc, const float* __restrict__ w1,
        unsigned short* __restrict__ h1b, float* __restrict__ st1o,
        int N, int Nb, int Nc) {
    __shared__ float w1s[1024];
    __shared__ unsigned int tbuf[32 * 260];
    int t = threadIdx.x;
    for (int i = t; i < 1024; i += 256) w1s[i] = w1[i];
    __syncthreads();
    int p = blockIdx.x * 256 + t;
    int pc = min(p, N - 1);
    float x = pts[pc * 5 + 1], y = pts[pc * 5 + 2], z = pts[pc * 5 + 3], inten = pts[pc * 5 + 4];
    float ph = pcyl[pc * 3 + 0], zc = pcyl[pc * 3 + 1], rho = pcyl[pc * 3 + 2];
    float ci0 = cylidx[pc * 2 + 0], ci1 = cylidx[pc * 2 + 1];
    float bi0 = bevidx[pc * 2 + 0], bi1 = bevidx[pc * 2 + 1];
    float bc0 = floorf(bi0), bc1 = floorf(bi1);
    float cc0 = floorf(ci0), cc1 = floorf(ci1);
    int bv = binv[pc], cv = cinv[pc];
    const unsigned long long MASK44 = (1ull << 44) - 1ull;
    unsigned long long A = bacc[2 * (long)bv], Bq = bacc[2 * (long)bv + 1];
    float bcnt = (float)(A >> 44);
    float rb = 1.0f / bcnt;
    float bmx = (float)(A & MASK44) * (1.0f / 1048576.0f) * rb;
    float bmy = (float)Bq * (1.0f / 16777216.0f) * rb - 40.0f;
    unsigned long long Cq = cacc[2 * (long)cv], Dq = cacc[2 * (long)cv + 1];
    float ccnt = (float)(Cq >> 44);
    float rc = 1.0f / ccnt;
    float cmp = (float)(Cq & MASK44) * (1.0f / 16777216.0f) * rc - 3.14159265f;
    float cmz = (float)Dq * (1.0f / 16777216.0f) * rc - 3.0f;
    float f[16];
    f[0] = x; f[1] = y; f[2] = z;
    f[3] = ph; f[4] = zc; f[5] = rho;
    f[6] = x - ((bc0 + 0.5f) * 0.32f + 0.0f);
    f[7] = y - ((bc1 + 0.5f) * 0.32f + (-40.0f));
    f[8] = ph - ((cc0 + 0.5f) * CVS0 + CR0);
    f[9] = zc - ((cc1 + 0.5f) * CVS1 + CR1);
    f[10] = x - bmx; f[11] = y - bmy;
    f[12] = ph - cmp; f[13] = zc - cmz;
    f[14] = sqrtf(x * x + y * y + z * z);
    f[15] = inten;
    for (int c2 = 0; c2 < 32; c2++) {
        float s0 = 0.f, s1 = 0.f;
        const float* w0 = &w1s[(2 * c2) * 16];
        const float* w1p = &w1s[(2 * c2 + 1) * 16];
#pragma unroll
        for (int k = 0; k < 16; k++) {
            s0 = fmaf(f[k], w0[k], s0);
            s1 = fmaf(f[k], w1p[k], s1);
        }
        tbuf[c2 * 260 + t] = (unsigned)f2bf(s0) | ((unsigned)f2bf(s1) << 16);
    }
    __syncthreads();
#pragma unroll
    for (int r = 0; r < 4; r++) {
        int cid = t + 256 * r;
        int pp = cid >> 2;
        int gp = blockIdx.x * 256 + pp;
        if (gp < N) {
            int c2b = (cid & 3) * 8;
            uint4 A2, Bv;
            A2.x = tbuf[(c2b + 0) * 260 + pp];
            A2.y = tbuf[(c2b + 1) * 260 + pp];
            A2.z = tbuf[(c2b + 2) * 260 + pp];
            A2.w = tbuf[(c2b + 3) * 260 + pp];
            Bv.x = tbuf[(c2b + 4) * 260 + pp];
            Bv.y = tbuf[(c2b + 5) * 260 + pp];
            Bv.z = tbuf[(c2b + 6) * 260 + pp];
            Bv.w = tbuf[(c2b + 7) * 260 + pp];
            uint4* dst = (uint4*)(h1b + (long)gp * 64 + (cid & 3) * 16);
            dst[0] = A2;
            dst[1] = Bv;
        }
    }
    // ---- fused st1: per-(channel,group) partial over tbuf, LDS combine ----
    {
        int ch = t & 63, grp = t >> 6;
        int c2 = ch >> 1, sh = (ch & 1) << 4;
        int nval = min(256, N - blockIdx.x * 256);
        float ss = 0.f, qq = 0.f;
        for (int i = 0; i < 64; i++) {
            int pp = grp * 64 + i;
            if (pp < nval) {
                unsigned uw = tbuf[c2 * 260 + pp];
                float v = bf2f((unsigned short)(uw >> sh));
                ss += v;
                qq = fmaf(v, v, qq);
            }
        }
        __syncthreads();  // all reads of w1s finished long ago; safe to reuse
        w1s[t] = ss;
        w1s[256 + t] = qq;
        __syncthreads();
        if (t < 64) {
            float S = w1s[t] + w1s[64 + t] + w1s[128 + t] + w1s[192 + t];
            float Q = w1s[256 + t] + w1s[320 + t] + w1s[384 + t] + w1s[448 + t];
            float* dst = st1o + (blockIdx.x & 7) * 128;  // replica
            atomicAdd(&dst[t], S);
            atomicAdd(&dst[64 + t], Q);
        }
    }
}

// ---- GEMM2 via MFMA (BN1 coefs inline) + fused cyl scatter-max + fused st2 ----
// h2b stores ONLY channels 64..127 (pointwise half) as [N,64] bf16.
// Channels 0..63 go straight into the cyl grid as order-preserving max-keys.
// st2: quad-reduce -> cross-wave LDS reduce -> 256 atomics into replica.
__global__ __launch_bounds__(256, 2) void k_gemm2_mfma(const unsigned short* __restrict__ h1b,
        const float* __restrict__ w2, const float* __restrict__ st1R,
        const float* __restrict__ g1, const float* __restrict__ b1g, float invn,
        const float* __restrict__ pts, const float* __restrict__ cylidx,
        const float* __restrict__ g2full, unsigned int* __restrict__ gridk,
        unsigned short* __restrict__ h2b, float* __restrict__ st2o, int N) {
    __shared__ float redS[4][128], redQ[4][128];
    int t = threadIdx.x;
    int lane = t & 63;
    int c = lane & 15, quad = lane >> 4;
    int wv = t >> 6;
    int wid = (blockIdx.x * 256 + t) >> 6;
    int nw = gridDim.x * 4;
    bf16x8_t Bf[8][2];
#pragma unroll
    for (int tt = 0; tt < 8; tt++)
#pragma unroll
        for (int kc = 0; kc < 2; kc++) {
            const float* wr = w2 + (tt * 16 + c) * 64 + kc * 32 + quad * 8;
            float4 w0 = *(const float4*)wr;
            float4 w1 = *(const float4*)(wr + 4);
            ABu tmp;
            tmp.us[0] = f2bf(w0.x); tmp.us[1] = f2bf(w0.y);
            tmp.us[2] = f2bf(w0.z); tmp.us[3] = f2bf(w0.w);
            tmp.us[4] = f2bf(w1.x); tmp.us[5] = f2bf(w1.y);
            tmp.us[6] = f2bf(w1.z); tmp.us[7] = f2bf(w1.w);
            Bf[tt][kc] = tmp.bf;
        }
    float a1[16], b1[16];
#pragma unroll
    for (int kc = 0; kc < 2; kc++)
#pragma unroll
        for (int j = 0; j < 8; j++) {
            int ch = kc * 32 + quad * 8 + j;
            bn_ab8(st1R, g1, b1g, 64, ch, invn, a1[kc * 8 + j], b1[kc * 8 + j]);
        }
    unsigned sx[4];
#pragma unroll
    for (int tt = 0; tt < 4; tt++)
        sx[tt] = (g2full[tt * 16 + c] < 0.f) ? 0x80000000u : 0u;
    float s8[8], q8[8];
#pragma unroll
    for (int tt = 0; tt < 8; tt++) { s8[tt] = 0.f; q8[tt] = 0.f; }
    int ntiles = (N + 15) >> 4;
    for (int tile = wid; tile < ntiles; tile += nw) {
        int p0 = tile * 16;
        int pa = min(p0 + c, N - 1);
        int bsc = (int)pts[pa * 5];
        int ccx = (int)floorf(cylidx[pa * 2]);
        int ccy = (int)floorf(cylidx[pa * 2 + 1]);
        int cellbase = (((bsc * 512 + ccx) * 48) + ccy) * 64;
        bf16x8_t Af[2];
#pragma unroll
        for (int kc = 0; kc < 2; kc++) {
            ABu u;
            u.q = *(const uint4*)(h1b + (long)pa * 64 + kc * 32 + quad * 8);
            ABu o;
#pragma unroll
            for (int j = 0; j < 8; j++)
                o.us[j] = f2bf(bnr(bf2f(u.us[j]), a1[kc * 8 + j], b1[kc * 8 + j]));
            Af[kc] = o.bf;
        }
        f32x4_t acc[8];
#pragma unroll
        for (int tt = 0; tt < 8; tt++) acc[tt] = (f32x4_t){0.f, 0.f, 0.f, 0.f};
#pragma unroll
        for (int tt = 0; tt < 8; tt++) {
            acc[tt] = __builtin_amdgcn_mfma_f32_16x16x32_bf16(Af[0], Bf[tt][0], acc[tt], 0, 0, 0);
            acc[tt] = __builtin_amdgcn_mfma_f32_16x16x32_bf16(Af[1], Bf[tt][1], acc[tt], 0, 0, 0);
        }
#pragma unroll
        for (int r = 0; r < 4; r++) {
            int cb_r = __shfl(cellbase, quad * 4 + r);  // all lanes active here
            int pr = p0 + quad * 4 + r;
            bool ok = pr < N;
#pragma unroll
            for (int tt = 0; tt < 8; tt++) {
                unsigned short hv = f2bf(acc[tt][r]);
                if (ok) {
                    float xr = bf2f(hv);
                    s8[tt] += xr;
                    q8[tt] = fmaf(xr, xr, q8[tt]);
                    if (tt < 4) {
                        unsigned key = fkey(__uint_as_float(__float_as_uint(xr) ^ sx[tt]));
                        atomicMax(&gridk[cb_r + tt * 16 + c], key);  // fire-and-forget
                    } else {
                        h2b[(long)pr * 64 + (tt - 4) * 16 + c] = hv;
                    }
                }
            }
        }
    }
    // quad-reduce -> LDS cross-wave reduce -> one atomic per channel per block
#pragma unroll
    for (int tt = 0; tt < 8; tt++) {
        float ss = s8[tt], qq = q8[tt];
        ss += __shfl_xor(ss, 16); ss += __shfl_xor(ss, 32);
        qq += __shfl_xor(qq, 16); qq += __shfl_xor(qq, 32);
        if (quad == 0) { redS[wv][tt * 16 + c] = ss; redQ[wv][tt * 16 + c] = qq; }
    }
    __syncthreads();
    if (t < 128) {
        float S = redS[0][t] + redS[1][t] + redS[2][t] + redS[3][t];
        float Q = redQ[0][t] + redQ[1][t] + redQ[2][t] + redQ[3][t];
        float* dst = st2o + (blockIdx.x & 7) * 256;  // replica
        atomicAdd(&dst[t], S);
        atomicAdd(&dst[128 + t], Q);
    }
}

// ---- 3x3 conv, LDS-staged implicit-GEMM MFMA; input = encoded max-keys,
// ---- decoded + BN2-ReLU'd at load time; stC: LDS reduce -> replica atomics ----
__global__ __launch_bounds__(768) void k_conv_lds(const unsigned int* __restrict__ gridk,
        const unsigned short* __restrict__ wctb, unsigned short* __restrict__ cb,
        const float* __restrict__ st2R, const float* __restrict__ g2,
        const float* __restrict__ b2g, float invn, float* __restrict__ stCo) {
    __shared__ unsigned short in_s[4 * 50 * 64];
    __shared__ unsigned short ob_s[2 * 48 * 64];
    __shared__ float as_[64], bs_[64];
    __shared__ float cS[12][16], cQ[12][16];
    int t = threadIdx.x;
    int lane = t & 63, wv = t >> 6;
    int n = lane & 15, quad = lane >> 4;
    int seg = wv >> 2, tt = wv & 3;
    int blk = blockIdx.x;
    int b = blk >> 8, r0 = (blk & 255) * 2;
    if (t < 64) {
        float av, bv;
        bn_ab8(st2R, g2, b2g, 128, t, invn, av, bv);
        as_[t] = fabsf(av);
        bs_[t] = bv;
    }
    bf16x8_t Bf[9][2];
    const unsigned short* wb = wctb + quad * 512 + (tt * 16 + n) * 8;
#pragma unroll
    for (int tap = 0; tap < 9; tap++)
#pragma unroll
        for (int kc = 0; kc < 2; kc++) {
            ABu u;
            u.q = *(const uint4*)(wb + (tap * 2 + kc) * 2048);
            Bf[tap][kc] = u.bf;
        }
    __syncthreads();  // a/b table ready
    for (int c = t; c < 1600; c += 768) {
        int row4 = c / 400;
        int rem = c % 400;
        int px = rem >> 3, ch8 = rem & 7;
        int gr = r0 + row4 - 1, gw = px - 1;
        ABu o;
        if (gr >= 0 && gr < 512 && gw >= 0 && gw < 48) {
            const unsigned int* src = gridk + (((long)b * 512 + gr) * 48 + gw) * 64 + ch8 * 8;
            uint4 k0 = *(const uint4*)src;
            uint4 k1 = *(const uint4*)(src + 4);
            const float* ap = &as_[ch8 * 8];
            const float* bp = &bs_[ch8 * 8];
            o.us[0] = f2bf(dec_key(k0.x, ap[0], bp[0]));
            o.us[1] = f2bf(dec_key(k0.y, ap[1], bp[1]));
            o.us[2] = f2bf(dec_key(k0.z, ap[2], bp[2]));
            o.us[3] = f2bf(dec_key(k0.w, ap[3], bp[3]));
            o.us[4] = f2bf(dec_key(k1.x, ap[4], bp[4]));
            o.us[5] = f2bf(dec_key(k1.y, ap[5], bp[5]));
            o.us[6] = f2bf(dec_key(k1.z, ap[6], bp[6]));
            o.us[7] = f2bf(dec_key(k1.w, ap[7], bp[7]));
        } else {
            o.q = make_uint4(0, 0, 0, 0);
        }
        *(uint4*)&in_s[(row4 * 50 + px) * 64 + ((ch8 ^ (px & 7)) << 3)] = o.q;
    }
    __syncthreads();
    float sC = 0.f, qC = 0.f;  // fused stC: channel tt*16+n (quad-invariant)
    for (int rr = 0; rr < 2; rr++) {
        f32x4_t acc0 = (f32x4_t){0.f, 0.f, 0.f, 0.f};
        f32x4_t acc1 = (f32x4_t){0.f, 0.f, 0.f, 0.f};
#pragma unroll
        for (int tap = 0; tap < 9; tap++) {
            int row4 = tap / 3 + rr;
            int lpx = seg * 16 + n + tap % 3;
            const unsigned short* base = &in_s[(row4 * 50 + lpx) * 64];
            ABu a0, a1;
            a0.q = *(const uint4*)(base + ((quad ^ (lpx & 7)) << 3));
            a1.q = *(const uint4*)(base + (((4 + quad) ^ (lpx & 7)) << 3));
            acc0 = __builtin_amdgcn_mfma_f32_16x16x32_bf16(a0.bf, Bf[tap][0], acc0, 0, 0, 0);
            acc1 = __builtin_amdgcn_mfma_f32_16x16x32_bf16(a1.bf, Bf[tap][1], acc1, 0, 0, 0);
        }
#pragma unroll
        for (int r2 = 0; r2 < 4; r2++) {
            int px = seg * 16 + quad * 4 + r2;
            unsigned short hv = f2bf(acc0[r2] + acc1[r2]);
            ob_s[(rr * 48 + px) * 64 + tt * 16 + n] = hv;
            float xr = bf2f(hv);
            sC += xr;
            qC = fmaf(xr, xr, qC);
        }
    }
    sC += __shfl_xor(sC, 16); sC += __shfl_xor(sC, 32);
    qC += __shfl_xor(qC, 16); qC += __shfl_xor(qC, 32);
    if (quad == 0) { cS[wv][n] = sC; cQ[wv][n] = qC; }
    __syncthreads();  // ob_s ready + cS/cQ ready
    if (t < 64) {
        int tt_ = t >> 4, n_ = t & 15;
        float S = cS[tt_][n_] + cS[tt_ + 4][n_] + cS[tt_ + 8][n_];
        float Q = cQ[tt_][n_] + cQ[tt_ + 4][n_] + cQ[tt_ + 8][n_];
        float* dst = stCo + (blockIdx.x & 7) * 128;  // replica
        atomicAdd(&dst[t], S);
        atomicAdd(&dst[64 + t], Q);
    }
    unsigned short* dst = cb + ((long)b * 512 + r0) * 48 * 64;
    *(uint4*)(dst + t * 8) = *(const uint4*)(ob_s + t * 8);
}

// ---- bilinear gather + GEMM3 via MFMA -> h3 row-major bf16 + fused st3 ----
__global__ __launch_bounds__(256, 2) void k_gather3_mfma(const unsigned short* __restrict__ h2b,
        const unsigned short* __restrict__ convb, const float* __restrict__ st2R,
        const float* __restrict__ g2, const float* __restrict__ b2g,
        const float* __restrict__ stCR, const float* __restrict__ gc,
        const float* __restrict__ bcg, float invn, float invnC,
        const float* __restrict__ cylidx, const float* __restrict__ pts,
        const float* __restrict__ w3, unsigned short* __restrict__ h3b,
        float* __restrict__ st3o, int N) {
    __shared__ float rS[4][64], rQ[4][64];
    int t = threadIdx.x;
    int lane = t & 63;
    int c = lane & 15, quad = lane >> 4;
    int wv = t >> 6;
    int wid = (blockIdx.x * 256 + t) >> 6;
    int nw = gridDim.x * 4;
    bf16x8_t Bf[4][4];
#pragma unroll
    for (int tt = 0; tt < 4; tt++)
#pragma unroll
        for (int kc = 0; kc < 4; kc++) {
            const float* wr = w3 + (tt * 16 + c) * 128 + kc * 32 + quad * 8;
            float4 w0 = *(const float4*)wr;
            float4 w1 = *(const float4*)(wr + 4);
            ABu tmp;
            tmp.us[0] = f2bf(w0.x); tmp.us[1] = f2bf(w0.y);
            tmp.us[2] = f2bf(w0.z); tmp.us[3] = f2bf(w0.w);
            tmp.us[4] = f2bf(w1.x); tmp.us[5] = f2bf(w1.y);
            tmp.us[6] = f2bf(w1.z); tmp.us[7] = f2bf(w1.w);
            Bf[tt][kc] = tmp.bf;
        }
    float a2[16], b2[16], aC[16], bC[16];
#pragma unroll
    for (int kc = 0; kc < 2; kc++)
#pragma unroll
        for (int j = 0; j < 8; j++) {
            int kk = kc * 32 + quad * 8 + j;
            bn_ab8(st2R, g2, b2g, 128, 64 + kk, invn, a2[kc * 8 + j], b2[kc * 8 + j]);
            bn_ab8(stCR, gc, bcg, 64, kk, invnC, aC[kc * 8 + j], bC[kc * 8 + j]);
        }
    float s4[4], q4[4];
#pragma unroll
    for (int tt = 0; tt < 4; tt++) { s4[tt] = 0.f; q4[tt] = 0.f; }
    int ntiles = (N + 15) >> 4;
    for (int tile = wid; tile < ntiles; tile += nw) {
        int p0 = tile * 16;
        int p = min(p0 + c, N - 1);
        float yq = cylidx[p * 2], xq = cylidx[p * 2 + 1];
        int b = (int)pts[p * 5];
        int xf = (int)floorf(xq), yf = (int)floorf(yq);
        int x0 = min(max(xf, 0), 47);
        int x1 = min(max(xf + 1, 0), 47);
        int y0 = min(max(yf, 0), 511);
        int y1 = min(max(yf + 1, 0), 511);
        float x0f = (float)x0, x1f = (float)x1, y0f = (float)y0, y1f = (float)y1;
        float wa = (x1f - xq) * (y1f - yq);
        float wb = (x1f - xq) * (yq - y0f);
        float wc2 = (xq - x0f) * (y1f - yq);
        float wd = (xq - x0f) * (yq - y0f);
        const unsigned short* Ia = convb + (((long)b * 512 + y0) * 48 + x0) * 64;
        const unsigned short* Ib = convb + (((long)b * 512 + y1) * 48 + x0) * 64;
        const unsigned short* Ic = convb + (((long)b * 512 + y0) * 48 + x1) * 64;
        const unsigned short* Id = convb + (((long)b * 512 + y1) * 48 + x1) * 64;
        bf16x8_t Af[4];
#pragma unroll
        for (int kc = 0; kc < 2; kc++) {
            ABu u;
            u.q = *(const uint4*)(h2b + (long)p * 64 + kc * 32 + quad * 8);
            ABu o;
#pragma unroll
            for (int j = 0; j < 8; j++)
                o.us[j] = f2bf(bnr(bf2f(u.us[j]), a2[kc * 8 + j], b2[kc * 8 + j]));
            Af[kc] = o.bf;
        }
#pragma unroll
        for (int kc = 0; kc < 2; kc++) {
            int cbo = kc * 32 + quad * 8;
            ABu ua, ub, uc, ud;
            ua.q = *(const uint4*)(Ia + cbo);
            ub.q = *(const uint4*)(Ib + cbo);
            uc.q = *(const uint4*)(Ic + cbo);
            ud.q = *(const uint4*)(Id + cbo);
            ABu o;
#pragma unroll
            for (int j = 0; j < 8; j++) {
                float aa = aC[kc * 8 + j], bbv = bC[kc * 8 + j];
                float v = wa * bnr(bf2f(ua.us[j]), aa, bbv) + wb * bnr(bf2f(ub.us[j]), aa, bbv)
                        + wc2 * bnr(bf2f(uc.us[j]), aa, bbv) + wd * bnr(bf2f(ud.us[j]), aa, bbv);
                o.us[j] = f2bf(v);
            }
            Af[2 + kc] = o.bf;
        }
        f32x4_t acc[4];
#pragma unroll
        for (int tt = 0; tt < 4; tt++) acc[tt] = (f32x4_t){0.f, 0.f, 0.f, 0.f};
#pragma unroll
        for (int tt = 0; tt < 4; tt++)
#pragma unroll
            for (int kc = 0; kc < 4; kc++)
                acc[tt] = __builtin_amdgcn_mfma_f32_16x16x32_bf16(Af[kc], Bf[tt][kc], acc[tt], 0, 0, 0);
#pragma unroll
        for (int tt = 0; tt < 4; tt++)
#pragma unroll
            for (int r = 0; r < 4; r++) {
                int pr = p0 + quad * 4 + r;
                if (pr < N) {
                    unsigned short hv = f2bf(acc[tt][r]);
                    h3b[(long)pr * 64 + tt * 16 + c] = hv;
                    float xr = bf2f(hv);
                    s4[tt] += xr;
                    q4[tt] = fmaf(xr, xr, q4[tt]);
                }
            }
    }
    // quad-reduce -> LDS cross-wave reduce -> one atomic per channel per block
#pragma unroll
    for (int tt = 0; tt < 4; tt++) {
        float ss = s4[tt], qq = q4[tt];
        ss += __shfl_xor(ss, 16); ss += __shfl_xor(ss, 32);
        qq += __shfl_xor(qq, 16); qq += __shfl_xor(qq, 32);
        if (quad == 0) { rS[wv][tt * 16 + c] = ss; rQ[wv][tt * 16 + c] = qq; }
    }
    __syncthreads();
    if (t < 64) {
        float S = rS[0][t] + rS[1][t] + rS[2][t] + rS[3][t];
        float Q = rQ[0][t] + rQ[1][t] + rQ[2][t] + rQ[3][t];
        float* dst = st3o + (blockIdx.x & 7) * 128;  // replica
        atomicAdd(&dst[t], S);
        atomicAdd(&dst[64 + t], Q);
    }
}

// ---- final BN-ReLU -> out_fea fp32 + bev scatter-max + voxel coords ----
// 16 points per 256-thread block; each thread owns 4 channels of one point.
// ushort4 h3b load (8B), float4 out_fea store (16B), uint4 pre-check for atomics.
__global__ __launch_bounds__(256) void k_out_tile3(const unsigned short* __restrict__ h3b,
        const float* __restrict__ st3R, const float* __restrict__ g3,
        const float* __restrict__ b3g, float invn, const int* __restrict__ binv,
        float* __restrict__ out_fea, unsigned int* __restrict__ out_bev,
        const int* __restrict__ bcoords, float* __restrict__ out_vc, int Nb, int N) {
    __shared__ float as_[64], bs_[64];
    int t = threadIdx.x;
    if (t < 64) {
        float a, bb;
        bn_ab8(st3R, g3, b3g, 64, t, invn, a, bb);
        as_[t] = a;
        bs_[t] = bb;
    }
    long gid = (long)blockIdx.x * 256 + t;
    if (gid < Nb) {
        int cc = bcoords[gid];
        int vb = cc / BEV_SXY;
        int rem = cc % BEV_SXY;
        int vx = rem / BEV_SY;
        int vy = rem % BEV_SY;
        out_vc[gid * 4 + 0] = (float)vb;
        out_vc[gid * 4 + 1] = 0.f;
        out_vc[gid * 4 + 2] = (float)vy;
        out_vc[gid * 4 + 3] = (float)vx;
    }
    __syncthreads();
    int p = blockIdx.x * 16 + (t >> 4);
    if (p >= N) return;
    int cg = (t & 15) * 4;
    ushort4 hv = *(const ushort4*)(h3b + (long)p * 64 + cg);
    float4 v;
    v.x = bnr(bf2f(hv.x), as_[cg + 0], bs_[cg + 0]);
    v.y = bnr(bf2f(hv.y), as_[cg + 1], bs_[cg + 1]);
    v.z = bnr(bf2f(hv.z), as_[cg + 2], bs_[cg + 2]);
    v.w = bnr(bf2f(hv.w), as_[cg + 3], bs_[cg + 3]);
    *(float4*)(out_fea + (long)p * 64 + cg) = v;
    int bi = binv[p];
    unsigned* cell = out_bev + (long)bi * 64 + cg;
    uint4 cur = *(const uint4*)cell;
    if (v.x > 0.f && __float_as_uint(v.x) > cur.x) atomicMax(&cell[0], __float_as_uint(v.x));
    if (v.y > 0.f && __float_as_uint(v.y) > cur.y) atomicMax(&cell[1], __float_as_uint(v.y));
    if (v.z > 0.f && __float_as_uint(v.z) > cur.z) atomicMax(&cell[2], __float_as_uint(v.z));
    if (v.w > 0.f && __float_as_uint(v.w) > cur.w) atomicMax(&cell[3], __float_as_uint(v.w));
}

extern "C" void kernel_launch(void* const* d_in, const int* in_sizes, int n_in,
                              void* d_out, int out_size, void* d_ws, size_t ws_size,
                              hipStream_t stream) {
    const float* pts = (const float*)d_in[0];
    const float* pcyl = (const float*)d_in[1];
    const float* cylidx = (const float*)d_in[2];
    const float* bevidx = (const float*)d_in[3];
    const float* w1 = (const float*)d_in[4];
    const float* g1 = (const float*)d_in[5];
    const float* b1 = (const float*)d_in[6];
    const float* w2 = (const float*)d_in[7];
    const float* g2 = (const float*)d_in[8];
    const float* b2 = (const float*)d_in[9];
    const float* wc = (const float*)d_in[10];
    const float* gc = (const float*)d_in[11];
    const float* bc = (const float*)d_in[12];
    const float* w3 = (const float*)d_in[13];
    const float* g3 = (const float*)d_in[14];
    const float* b3 = (const float*)d_in[15];
    const int* binv = (const int*)d_in[16];
    const int* bcoords = (const int*)d_in[17];
    const int* cinv = (const int*)d_in[18];
    const int* ccoords = (const int*)d_in[19];
    int N = in_sizes[0] / 5;
    int Nb = in_sizes[17];
    int Nc = in_sizes[19];
    const int B = 4;
    const long GRIDSZ = (long)B * 512 * 48 * 64;
    float invN = 1.0f / (float)N;
    float invC = 1.0f / (float)(B * 512 * 48);

    char* wsb = (char*)d_ws;
    unsigned short* wctb = (unsigned short*)wsb;                      // 73728 B
    unsigned short* h2b = (unsigned short*)(wsb + 73728);             // [N,64] bf16 (pointwise)
    unsigned short* h13b = (unsigned short*)(wsb + 73728 + 128L * N); // [N,64] bf16
    unsigned int* gridk = (unsigned int*)(wsb + 73728 + 256L * N);    // u32 max-keys
    unsigned short* convb = (unsigned short*)(gridk + GRIDSZ);        // bf16 conv output
    unsigned long long* bacc = (unsigned long long*)(convb + GRIDSZ); // 2*Nb u64
    unsigned long long* cacc = bacc + 2L * Nb;                        // 2*Nc u64
    float* stats = (float*)(cacc + 2L * Nc);                          // 5120 floats (8-way replicas)
    float* st1R = stats;               // 8 * 128
    float* st2R = stats + 1024;        // 8 * 256
    float* st3R = stats + 3072;        // 8 * 128
    float* stCR = stats + 4096;        // 8 * 128

    float* out_fea = (float*)d_out;
    unsigned int* out_bev = (unsigned int*)((float*)d_out + (long)N * 64);
    float* out_vc = (float*)d_out + (long)N * 64 + (long)Nb * 64;

    hipMemsetAsync(gridk, 0, (size_t)GRIDSZ * 4, stream);
    hipMemsetAsync(bacc, 0, (size_t)((2L * Nb + 2L * Nc) * 8 + 5120 * 4), stream);
    hipMemsetAsync(out_bev, 0, (size_t)Nb * 64 * 4, stream);

    int nb256 = (N + 255) / 256;
    k_scatter_sums<<<nb256, 256, 0, stream>>>(pts, pcyl, binv, cinv, wc, wctb, bacc, cacc, N, Nb, Nc);
    k_feat_gemm1<<<nb256, 256, 0, stream>>>(pts, pcyl, cylidx, bevidx, binv, cinv, bacc, cacc, w1, h13b, st1R, N, Nb, Nc);
    k_gemm2_mfma<<<512, 256, 0, stream>>>(h13b, w2, st1R, g1, b1, invN, pts, cylidx, g2, gridk, h2b, st2R, N);
    k_conv_lds<<<1024, 768, 0, stream>>>(gridk, wctb, convb, st2R, g2, b2, invN, stCR);
    k_gather3_mfma<<<512, 256, 0, stream>>>(h2b, convb, st2R, g2, b2, stCR, gc, bc, invN, invC, cylidx, pts, w3, h13b, st3R, N);
    k_out_tile3<<<(N + 15) / 16, 256, 0, stream>>>(h13b, st3R, g3, b3, invN, binv, out_fea, out_bev, bcoords, out_vc, Nb, N);
}

// Round 8
// 368.380 us; speedup vs baseline: 1.2083x; 1.2083x over previous
//
#include <hip/hip_runtime.h>
#include <math.h>

#define BN_EPS 1e-3f

static constexpr float CR0 = -3.14159265f;
static constexpr float CR1 = -2.0f;
static constexpr float CVS0 = (float)((3.14159265 * 2.0) / 512.0);
static constexpr float CVS1 = (float)(6.0 / 48.0);
#define BEV_SXY (220 * 250)
#define BEV_SY 250

typedef __attribute__((ext_vector_type(8))) __bf16 bf16x8_t;
typedef __attribute__((ext_vector_type(4))) float f32x4_t;

union ABu { uint4 q; unsigned short us[8]; bf16x8_t bf; };

__device__ __forceinline__ float bnr(float x, float a, float b) {
    float v = fmaf(x, a, b);
    return v > 0.f ? v : 0.f;
}
__device__ __forceinline__ float bf2f(unsigned short u) {
    return __uint_as_float(((unsigned)u) << 16);
}
__device__ __forceinline__ unsigned short f2bf(float f) {
    unsigned u = __float_as_uint(f);
    u += 0x7FFFu + ((u >> 16) & 1u);
    return (unsigned short)(u >> 16);
}
// BN coefs from 8-way replicated stats: stR[r*2C + ch] = sum, stR[r*2C + C + ch] = sumsq
__device__ __forceinline__ void bn_ab8(const float* stR, const float* g, const float* b,
                                       int C, int ch, float invn, float& a, float& bb) {
    float sm = 0.f, sq = 0.f;
#pragma unroll
    for (int r = 0; r < 8; r++) {
        sm += stR[r * 2 * C + ch];
        sq += stR[r * 2 * C + C + ch];
    }
    float m = sm * invn;
    float var = sq * invn - m * m;
    a = g[ch] * rsqrtf(var + BN_EPS);
    bb = b[ch] - m * a;
}

// order-preserving float->u32 key (key==0 reserved as "empty": only -NaN maps there)
__device__ __forceinline__ unsigned fkey(float f) {
    unsigned u = __float_as_uint(f);
    return (u & 0x80000000u) ? ~u : (u | 0x80000000u);
}
__device__ __forceinline__ float dec_key(unsigned k, float a, float b) {
    if (k == 0u) return 0.f;
    unsigned u = (k & 0x80000000u) ? (k ^ 0x80000000u) : ~k;
    float v = fmaf(__uint_as_float(u), a, b);
    return v > 0.f ? v : 0.f;
}

// ---- segment sums (u64 fixed-point packed atomics) + conv-weight pre-pack ----
__global__ void k_scatter_sums(const float* __restrict__ pts, const float* __restrict__ pcyl,
                               const int* __restrict__ binv, const int* __restrict__ cinv,
                               const float* __restrict__ wc, unsigned short* __restrict__ wctb,
                               unsigned long long* __restrict__ bacc,
                               unsigned long long* __restrict__ cacc,
                               int N, int Nb, int Nc) {
    int p = blockIdx.x * blockDim.x + threadIdx.x;
    if (p < 9 * 4096) {
        int j = p & 7, oc = (p >> 3) & 63, quad = (p >> 9) & 3, kc = (p >> 11) & 1, tap = p >> 12;
        int ic = kc * 32 + quad * 8 + j;
        wctb[p] = f2bf(wc[((oc * 64 + ic) * 3 + tap / 3) * 3 + tap % 3]);
    }
    if (p >= N) return;
    float x = pts[p * 5 + 1], y = pts[p * 5 + 2];
    float ph = pcyl[p * 3 + 0], z = pcyl[p * 3 + 1];
    int bi = binv[p], ci = cinv[p];
    unsigned long long xa = (1ull << 44) + (unsigned long long)(x * 1048576.0f + 0.5f);
    unsigned long long ya = (unsigned long long)((y + 40.0f) * 16777216.0f + 0.5f);
    unsigned long long pa = (1ull << 44) + (unsigned long long)((ph + 3.14159265f) * 16777216.0f + 0.5f);
    unsigned long long za = (unsigned long long)((z + 3.0f) * 16777216.0f + 0.5f);
    atomicAdd(&bacc[2 * (long)bi], xa);
    atomicAdd(&bacc[2 * (long)bi + 1], ya);
    atomicAdd(&cacc[2 * (long)ci], pa);
    atomicAdd(&cacc[2 * (long)ci + 1], za);
}

// ---- 16-feat build + GEMM1 (16->64), h1 row-major bf16 via LDS transpose ----
// st1 fused: per-block LDS reduce -> 128 atomics into replica (blockIdx&7).
__global__ __launch_bounds__(256) void k_feat_gemm1(const float* __restrict__ pts,
        const float* __restrict__ pcyl, const float* __restrict__ cylidx,
        const float* __restrict__ bevidx, const int* __restrict__ binv,
        const int* __restrict__ cinv, const unsigned long long* __restrict__ bacc,
        const unsigned long long* __restrict__ cacc, const float* __restrict__ w1,
        unsigned short* __restrict__ h1b, float* __restrict__ st1o,
        int N, int Nb, int Nc) {
    __shared__ float w1s[1024];
    __shared__ unsigned int tbuf[32 * 260];
    int t = threadIdx.x;
    for (int i = t; i < 1024; i += 256) w1s[i] = w1[i];
    __syncthreads();
    int p = blockIdx.x * 256 + t;
    int pc = min(p, N - 1);
    float x = pts[pc * 5 + 1], y = pts[pc * 5 + 2], z = pts[pc * 5 + 3], inten = pts[pc * 5 + 4];
    float ph = pcyl[pc * 3 + 0], zc = pcyl[pc * 3 + 1], rho = pcyl[pc * 3 + 2];
    float ci0 = cylidx[pc * 2 + 0], ci1 = cylidx[pc * 2 + 1];
    float bi0 = bevidx[pc * 2 + 0], bi1 = bevidx[pc * 2 + 1];
    float bc0 = floorf(bi0), bc1 = floorf(bi1);
    float cc0 = floorf(ci0), cc1 = floorf(ci1);
    int bv = binv[pc], cv = cinv[pc];
    const unsigned long long MASK44 = (1ull << 44) - 1ull;
    unsigned long long A = bacc[2 * (long)bv], Bq = bacc[2 * (long)bv + 1];
    float bcnt = (float)(A >> 44);
    float rb = 1.0f / bcnt;
    float bmx = (float)(A & MASK44) * (1.0f / 1048576.0f) * rb;
    float bmy = (float)Bq * (1.0f / 16777216.0f) * rb - 40.0f;
    unsigned long long Cq = cacc[2 * (long)cv], Dq = cacc[2 * (long)cv + 1];
    float ccnt = (float)(Cq >> 44);
    float rc = 1.0f / ccnt;
    float cmp = (float)(Cq & MASK44) * (1.0f / 16777216.0f) * rc - 3.14159265f;
    float cmz = (float)Dq * (1.0f / 16777216.0f) * rc - 3.0f;
    float f[16];
    f[0] = x; f[1] = y; f[2] = z;
    f[3] = ph; f[4] = zc; f[5] = rho;
    f[6] = x - ((bc0 + 0.5f) * 0.32f + 0.0f);
    f[7] = y - ((bc1 + 0.5f) * 0.32f + (-40.0f));
    f[8] = ph - ((cc0 + 0.5f) * CVS0 + CR0);
    f[9] = zc - ((cc1 + 0.5f) * CVS1 + CR1);
    f[10] = x - bmx; f[11] = y - bmy;
    f[12] = ph - cmp; f[13] = zc - cmz;
    f[14] = sqrtf(x * x + y * y + z * z);
    f[15] = inten;
    for (int c2 = 0; c2 < 32; c2++) {
        float s0 = 0.f, s1 = 0.f;
        const float* w0 = &w1s[(2 * c2) * 16];
        const float* w1p = &w1s[(2 * c2 + 1) * 16];
#pragma unroll
        for (int k = 0; k < 16; k++) {
            s0 = fmaf(f[k], w0[k], s0);
            s1 = fmaf(f[k], w1p[k], s1);
        }
        tbuf[c2 * 260 + t] = (unsigned)f2bf(s0) | ((unsigned)f2bf(s1) << 16);
    }
    __syncthreads();
#pragma unroll
    for (int r = 0; r < 4; r++) {
        int cid = t + 256 * r;
        int pp = cid >> 2;
        int gp = blockIdx.x * 256 + pp;
        if (gp < N) {
            int c2b = (cid & 3) * 8;
            uint4 A2, Bv;
            A2.x = tbuf[(c2b + 0) * 260 + pp];
            A2.y = tbuf[(c2b + 1) * 260 + pp];
            A2.z = tbuf[(c2b + 2) * 260 + pp];
            A2.w = tbuf[(c2b + 3) * 260 + pp];
            Bv.x = tbuf[(c2b + 4) * 260 + pp];
            Bv.y = tbuf[(c2b + 5) * 260 + pp];
            Bv.z = tbuf[(c2b + 6) * 260 + pp];
            Bv.w = tbuf[(c2b + 7) * 260 + pp];
            uint4* dst = (uint4*)(h1b + (long)gp * 64 + (cid & 3) * 16);
            dst[0] = A2;
            dst[1] = Bv;
        }
    }
    // ---- fused st1: per-(channel,group) partial over tbuf, LDS combine ----
    {
        int ch = t & 63, grp = t >> 6;
        int c2 = ch >> 1, sh = (ch & 1) << 4;
        int nval = min(256, N - blockIdx.x * 256);
        float ss = 0.f, qq = 0.f;
        for (int i = 0; i < 64; i++) {
            int pp = grp * 64 + i;
            if (pp < nval) {
                unsigned uw = tbuf[c2 * 260 + pp];
                float v = bf2f((unsigned short)(uw >> sh));
                ss += v;
                qq = fmaf(v, v, qq);
            }
        }
        __syncthreads();  // all reads of w1s finished long ago; safe to reuse
        w1s[t] = ss;
        w1s[256 + t] = qq;
        __syncthreads();
        if (t < 64) {
            float S = w1s[t] + w1s[64 + t] + w1s[128 + t] + w1s[192 + t];
            float Q = w1s[256 + t] + w1s[320 + t] + w1s[384 + t] + w1s[448 + t];
            float* dst = st1o + (blockIdx.x & 7) * 128;  // replica
            atomicAdd(&dst[t], S);
            atomicAdd(&dst[64 + t], Q);
        }
    }
}

// ---- GEMM2 via MFMA (BN1 coefs inline) + fused cyl scatter-max + fused st2 ----
// h2b stores ONLY channels 64..127 (pointwise half) as [N,64] bf16.
// Channels 0..63 go straight into the cyl grid as order-preserving max-keys.
// st2: quad-reduce -> cross-wave LDS reduce -> 256 atomics into replica.
__global__ __launch_bounds__(256, 2) void k_gemm2_mfma(const unsigned short* __restrict__ h1b,
        const float* __restrict__ w2, const float* __restrict__ st1R,
        const float* __restrict__ g1, const float* __restrict__ b1g, float invn,
        const float* __restrict__ pts, const float* __restrict__ cylidx,
        const float* __restrict__ g2full, unsigned int* __restrict__ gridk,
        unsigned short* __restrict__ h2b, float* __restrict__ st2o, int N) {
    __shared__ float redS[4][128], redQ[4][128];
    int t = threadIdx.x;
    int lane = t & 63;
    int c = lane & 15, quad = lane >> 4;
    int wv = t >> 6;
    int wid = (blockIdx.x * 256 + t) >> 6;
    int nw = gridDim.x * 4;
    bf16x8_t Bf[8][2];
#pragma unroll
    for (int tt = 0; tt < 8; tt++)
#pragma unroll
        for (int kc = 0; kc < 2; kc++) {
            const float* wr = w2 + (tt * 16 + c) * 64 + kc * 32 + quad * 8;
            float4 w0 = *(const float4*)wr;
            float4 w1 = *(const float4*)(wr + 4);
            ABu tmp;
            tmp.us[0] = f2bf(w0.x); tmp.us[1] = f2bf(w0.y);
            tmp.us[2] = f2bf(w0.z); tmp.us[3] = f2bf(w0.w);
            tmp.us[4] = f2bf(w1.x); tmp.us[5] = f2bf(w1.y);
            tmp.us[6] = f2bf(w1.z); tmp.us[7] = f2bf(w1.w);
            Bf[tt][kc] = tmp.bf;
        }
    float a1[16], b1[16];
#pragma unroll
    for (int kc = 0; kc < 2; kc++)
#pragma unroll
        for (int j = 0; j < 8; j++) {
            int ch = kc * 32 + quad * 8 + j;
            bn_ab8(st1R, g1, b1g, 64, ch, invn, a1[kc * 8 + j], b1[kc * 8 + j]);
        }
    unsigned sx[4];
#pragma unroll
    for (int tt = 0; tt < 4; tt++)
        sx[tt] = (g2full[tt * 16 + c] < 0.f) ? 0x80000000u : 0u;
    float s8[8], q8[8];
#pragma unroll
    for (int tt = 0; tt < 8; tt++) { s8[tt] = 0.f; q8[tt] = 0.f; }
    int ntiles = (N + 15) >> 4;
    for (int tile = wid; tile < ntiles; tile += nw) {
        int p0 = tile * 16;
        int pa = min(p0 + c, N - 1);
        int bsc = (int)pts[pa * 5];
        int ccx = (int)floorf(cylidx[pa * 2]);
        int ccy = (int)floorf(cylidx[pa * 2 + 1]);
        int cellbase = (((bsc * 512 + ccx) * 48) + ccy) * 64;
        bf16x8_t Af[2];
#pragma unroll
        for (int kc = 0; kc < 2; kc++) {
            ABu u;
            u.q = *(const uint4*)(h1b + (long)pa * 64 + kc * 32 + quad * 8);
            ABu o;
#pragma unroll
            for (int j = 0; j < 8; j++)
                o.us[j] = f2bf(bnr(bf2f(u.us[j]), a1[kc * 8 + j], b1[kc * 8 + j]));
            Af[kc] = o.bf;
        }
        f32x4_t acc[8];
#pragma unroll
        for (int tt = 0; tt < 8; tt++) acc[tt] = (f32x4_t){0.f, 0.f, 0.f, 0.f};
#pragma unroll
        for (int tt = 0; tt < 8; tt++) {
            acc[tt] = __builtin_amdgcn_mfma_f32_16x16x32_bf16(Af[0], Bf[tt][0], acc[tt], 0, 0, 0);
            acc[tt] = __builtin_amdgcn_mfma_f32_16x16x32_bf16(Af[1], Bf[tt][1], acc[tt], 0, 0, 0);
        }
#pragma unroll
        for (int r = 0; r < 4; r++) {
            int cb_r = __shfl(cellbase, quad * 4 + r);  // all lanes active here
            int pr = p0 + quad * 4 + r;
            bool ok = pr < N;
#pragma unroll
            for (int tt = 0; tt < 8; tt++) {
                unsigned short hv = f2bf(acc[tt][r]);
                if (ok) {
                    float xr = bf2f(hv);
                    s8[tt] += xr;
                    q8[tt] = fmaf(xr, xr, q8[tt]);
                    if (tt < 4) {
                        unsigned key = fkey(__uint_as_float(__float_as_uint(xr) ^ sx[tt]));
                        atomicMax(&gridk[cb_r + tt * 16 + c], key);  // fire-and-forget
                    } else {
                        h2b[(long)pr * 64 + (tt - 4) * 16 + c] = hv;
                    }
                }
            }
        }
    }
    // quad-reduce -> LDS cross-wave reduce -> one atomic per channel per block
#pragma unroll
    for (int tt = 0; tt < 8; tt++) {
        float ss = s8[tt], qq = q8[tt];
        ss += __shfl_xor(ss, 16); ss += __shfl_xor(ss, 32);
        qq += __shfl_xor(qq, 16); qq += __shfl_xor(qq, 32);
        if (quad == 0) { redS[wv][tt * 16 + c] = ss; redQ[wv][tt * 16 + c] = qq; }
    }
    __syncthreads();
    if (t < 128) {
        float S = redS[0][t] + redS[1][t] + redS[2][t] + redS[3][t];
        float Q = redQ[0][t] + redQ[1][t] + redQ[2][t] + redQ[3][t];
        float* dst = st2o + (blockIdx.x & 7) * 256;  // replica
        atomicAdd(&dst[t], S);
        atomicAdd(&dst[128 + t], Q);
    }
}

// ---- 3x3 conv, LDS-staged implicit-GEMM MFMA; input = encoded max-keys,
// ---- decoded + BN2-ReLU'd at load time; stC: LDS reduce -> replica atomics ----
__global__ __launch_bounds__(768) void k_conv_lds(const unsigned int* __restrict__ gridk,
        const unsigned short* __restrict__ wctb, unsigned short* __restrict__ cb,
        const float* __restrict__ st2R, const float* __restrict__ g2,
        const float* __restrict__ b2g, float invn, float* __restrict__ stCo) {
    __shared__ unsigned short in_s[4 * 50 * 64];
    __shared__ unsigned short ob_s[2 * 48 * 64];
    __shared__ float as_[64], bs_[64];
    __shared__ float cS[12][16], cQ[12][16];
    int t = threadIdx.x;
    int lane = t & 63, wv = t >> 6;
    int n = lane & 15, quad = lane >> 4;
    int seg = wv >> 2, tt = wv & 3;
    int blk = blockIdx.x;
    int b = blk >> 8, r0 = (blk & 255) * 2;
    if (t < 64) {
        float av, bv;
        bn_ab8(st2R, g2, b2g, 128, t, invn, av, bv);
        as_[t] = fabsf(av);
        bs_[t] = bv;
    }
    bf16x8_t Bf[9][2];
    const unsigned short* wb = wctb + quad * 512 + (tt * 16 + n) * 8;
#pragma unroll
    for (int tap = 0; tap < 9; tap++)
#pragma unroll
        for (int kc = 0; kc < 2; kc++) {
            ABu u;
            u.q = *(const uint4*)(wb + (tap * 2 + kc) * 2048);
            Bf[tap][kc] = u.bf;
        }
    __syncthreads();  // a/b table ready
    for (int c = t; c < 1600; c += 768) {
        int row4 = c / 400;
        int rem = c % 400;
        int px = rem >> 3, ch8 = rem & 7;
        int gr = r0 + row4 - 1, gw = px - 1;
        ABu o;
        if (gr >= 0 && gr < 512 && gw >= 0 && gw < 48) {
            const unsigned int* src = gridk + (((long)b * 512 + gr) * 48 + gw) * 64 + ch8 * 8;
            uint4 k0 = *(const uint4*)src;
            uint4 k1 = *(const uint4*)(src + 4);
            const float* ap = &as_[ch8 * 8];
            const float* bp = &bs_[ch8 * 8];
            o.us[0] = f2bf(dec_key(k0.x, ap[0], bp[0]));
            o.us[1] = f2bf(dec_key(k0.y, ap[1], bp[1]));
            o.us[2] = f2bf(dec_key(k0.z, ap[2], bp[2]));
            o.us[3] = f2bf(dec_key(k0.w, ap[3], bp[3]));
            o.us[4] = f2bf(dec_key(k1.x, ap[4], bp[4]));
            o.us[5] = f2bf(dec_key(k1.y, ap[5], bp[5]));
            o.us[6] = f2bf(dec_key(k1.z, ap[6], bp[6]));
            o.us[7] = f2bf(dec_key(k1.w, ap[7], bp[7]));
        } else {
            o.q = make_uint4(0, 0, 0, 0);
        }
        *(uint4*)&in_s[(row4 * 50 + px) * 64 + ((ch8 ^ (px & 7)) << 3)] = o.q;
    }
    __syncthreads();
    float sC = 0.f, qC = 0.f;  // fused stC: channel tt*16+n (quad-invariant)
    for (int rr = 0; rr < 2; rr++) {
        f32x4_t acc0 = (f32x4_t){0.f, 0.f, 0.f, 0.f};
        f32x4_t acc1 = (f32x4_t){0.f, 0.f, 0.f, 0.f};
#pragma unroll
        for (int tap = 0; tap < 9; tap++) {
            int row4 = tap / 3 + rr;
            int lpx = seg * 16 + n + tap % 3;
            const unsigned short* base = &in_s[(row4 * 50 + lpx) * 64];
            ABu a0, a1;
            a0.q = *(const uint4*)(base + ((quad ^ (lpx & 7)) << 3));
            a1.q = *(const uint4*)(base + (((4 + quad) ^ (lpx & 7)) << 3));
            acc0 = __builtin_amdgcn_mfma_f32_16x16x32_bf16(a0.bf, Bf[tap][0], acc0, 0, 0, 0);
            acc1 = __builtin_amdgcn_mfma_f32_16x16x32_bf16(a1.bf, Bf[tap][1], acc1, 0, 0, 0);
        }
#pragma unroll
        for (int r2 = 0; r2 < 4; r2++) {
            int px = seg * 16 + quad * 4 + r2;
            unsigned short hv = f2bf(acc0[r2] + acc1[r2]);
            ob_s[(rr * 48 + px) * 64 + tt * 16 + n] = hv;
            float xr = bf2f(hv);
            sC += xr;
            qC = fmaf(xr, xr, qC);
        }
    }
    sC += __shfl_xor(sC, 16); sC += __shfl_xor(sC, 32);
    qC += __shfl_xor(qC, 16); qC += __shfl_xor(qC, 32);
    if (quad == 0) { cS[wv][n] = sC; cQ[wv][n] = qC; }
    __syncthreads();  // ob_s ready + cS/cQ ready
    if (t < 64) {
        int tt_ = t >> 4, n_ = t & 15;
        float S = cS[tt_][n_] + cS[tt_ + 4][n_] + cS[tt_ + 8][n_];
        float Q = cQ[tt_][n_] + cQ[tt_ + 4][n_] + cQ[tt_ + 8][n_];
        float* dst = stCo + (blockIdx.x & 7) * 128;  // replica
        atomicAdd(&dst[t], S);
        atomicAdd(&dst[64 + t], Q);
    }
    unsigned short* dst = cb + ((long)b * 512 + r0) * 48 * 64;
    *(uint4*)(dst + t * 8) = *(const uint4*)(ob_s + t * 8);
}

// ---- bilinear gather + GEMM3 via MFMA -> h3 row-major bf16 + fused st3 ----
__global__ __launch_bounds__(256, 2) void k_gather3_mfma(const unsigned short* __restrict__ h2b,
        const unsigned short* __restrict__ convb, const float* __restrict__ st2R,
        const float* __restrict__ g2, const float* __restrict__ b2g,
        const float* __restrict__ stCR, const float* __restrict__ gc,
        const float* __restrict__ bcg, float invn, float invnC,
        const float* __restrict__ cylidx, const float* __restrict__ pts,
        const float* __restrict__ w3, unsigned short* __restrict__ h3b,
        float* __restrict__ st3o, int N) {
    __shared__ float rS[4][64], rQ[4][64];
    int t = threadIdx.x;
    int lane = t & 63;
    int c = lane & 15, quad = lane >> 4;
    int wv = t >> 6;
    int wid = (blockIdx.x * 256 + t) >> 6;
    int nw = gridDim.x * 4;
    bf16x8_t Bf[4][4];
#pragma unroll
    for (int tt = 0; tt < 4; tt++)
#pragma unroll
        for (int kc = 0; kc < 4; kc++) {
            const float* wr = w3 + (tt * 16 + c) * 128 + kc * 32 + quad * 8;
            float4 w0 = *(const float4*)wr;
            float4 w1 = *(const float4*)(wr + 4);
            ABu tmp;
            tmp.us[0] = f2bf(w0.x); tmp.us[1] = f2bf(w0.y);
            tmp.us[2] = f2bf(w0.z); tmp.us[3] = f2bf(w0.w);
            tmp.us[4] = f2bf(w1.x); tmp.us[5] = f2bf(w1.y);
            tmp.us[6] = f2bf(w1.z); tmp.us[7] = f2bf(w1.w);
            Bf[tt][kc] = tmp.bf;
        }
    float a2[16], b2[16], aC[16], bC[16];
#pragma unroll
    for (int kc = 0; kc < 2; kc++)
#pragma unroll
        for (int j = 0; j < 8; j++) {
            int kk = kc * 32 + quad * 8 + j;
            bn_ab8(st2R, g2, b2g, 128, 64 + kk, invn, a2[kc * 8 + j], b2[kc * 8 + j]);
            bn_ab8(stCR, gc, bcg, 64, kk, invnC, aC[kc * 8 + j], bC[kc * 8 + j]);
        }
    float s4[4], q4[4];
#pragma unroll
    for (int tt = 0; tt < 4; tt++) { s4[tt] = 0.f; q4[tt] = 0.f; }
    int ntiles = (N + 15) >> 4;
    for (int tile = wid; tile < ntiles; tile += nw) {
        int p0 = tile * 16;
        int p = min(p0 + c, N - 1);
        float yq = cylidx[p * 2], xq = cylidx[p * 2 + 1];
        int b = (int)pts[p * 5];
        int xf = (int)floorf(xq), yf = (int)floorf(yq);
        int x0 = min(max(xf, 0), 47);
        int x1 = min(max(xf + 1, 0), 47);
        int y0 = min(max(yf, 0), 511);
        int y1 = min(max(yf + 1, 0), 511);
        float x0f = (float)x0, x1f = (float)x1, y0f = (float)y0, y1f = (float)y1;
        float wa = (x1f - xq) * (y1f - yq);
        float wb = (x1f - xq) * (yq - y0f);
        float wc2 = (xq - x0f) * (y1f - yq);
        float wd = (xq - x0f) * (yq - y0f);
        const unsigned short* Ia = convb + (((long)b * 512 + y0) * 48 + x0) * 64;
        const unsigned short* Ib = convb + (((long)b * 512 + y1) * 48 + x0) * 64;
        const unsigned short* Ic = convb + (((long)b * 512 + y0) * 48 + x1) * 64;
        const unsigned short* Id = convb + (((long)b * 512 + y1) * 48 + x1) * 64;
        bf16x8_t Af[4];
#pragma unroll
        for (int kc = 0; kc < 2; kc++) {
            ABu u;
            u.q = *(const uint4*)(h2b + (long)p * 64 + kc * 32 + quad * 8);
            ABu o;
#pragma unroll
            for (int j = 0; j < 8; j++)
                o.us[j] = f2bf(bnr(bf2f(u.us[j]), a2[kc * 8 + j], b2[kc * 8 + j]));
            Af[kc] = o.bf;
        }
#pragma unroll
        for (int kc = 0; kc < 2; kc++) {
            int cbo = kc * 32 + quad * 8;
            ABu ua, ub, uc, ud;
            ua.q = *(const uint4*)(Ia + cbo);
            ub.q = *(const uint4*)(Ib + cbo);
            uc.q = *(const uint4*)(Ic + cbo);
            ud.q = *(const uint4*)(Id + cbo);
            ABu o;
#pragma unroll
            for (int j = 0; j < 8; j++) {
                float aa = aC[kc * 8 + j], bbv = bC[kc * 8 + j];
                float v = wa * bnr(bf2f(ua.us[j]), aa, bbv) + wb * bnr(bf2f(ub.us[j]), aa, bbv)
                        + wc2 * bnr(bf2f(uc.us[j]), aa, bbv) + wd * bnr(bf2f(ud.us[j]), aa, bbv);
                o.us[j] = f2bf(v);
            }
            Af[2 + kc] = o.bf;
        }
        f32x4_t acc[4];
#pragma unroll
        for (int tt = 0; tt < 4; tt++) acc[tt] = (f32x4_t){0.f, 0.f, 0.f, 0.f};
#pragma unroll
        for (int tt = 0; tt < 4; tt++)
#pragma unroll
            for (int kc = 0; kc < 4; kc++)
                acc[tt] = __builtin_amdgcn_mfma_f32_16x16x32_bf16(Af[kc], Bf[tt][kc], acc[tt], 0, 0, 0);
#pragma unroll
        for (int tt = 0; tt < 4; tt++)
#pragma unroll
            for (int r = 0; r < 4; r++) {
                int pr = p0 + quad * 4 + r;
                if (pr < N) {
                    unsigned short hv = f2bf(acc[tt][r]);
                    h3b[(long)pr * 64 + tt * 16 + c] = hv;
                    float xr = bf2f(hv);
                    s4[tt] += xr;
                    q4[tt] = fmaf(xr, xr, q4[tt]);
                }
            }
    }
    // quad-reduce -> LDS cross-wave reduce -> one atomic per channel per block
#pragma unroll
    for (int tt = 0; tt < 4; tt++) {
        float ss = s4[tt], qq = q4[tt];
        ss += __shfl_xor(ss, 16); ss += __shfl_xor(ss, 32);
        qq += __shfl_xor(qq, 16); qq += __shfl_xor(qq, 32);
        if (quad == 0) { rS[wv][tt * 16 + c] = ss; rQ[wv][tt * 16 + c] = qq; }
    }
    __syncthreads();
    if (t < 64) {
        float S = rS[0][t] + rS[1][t] + rS[2][t] + rS[3][t];
        float Q = rQ[0][t] + rQ[1][t] + rQ[2][t] + rQ[3][t];
        float* dst = st3o + (blockIdx.x & 7) * 128;  // replica
        atomicAdd(&dst[t], S);
        atomicAdd(&dst[64 + t], Q);
    }
}

// ---- final BN-ReLU -> out_fea fp32 + bev scatter-max + voxel coords ----
// (R5 version: one wave per point, lane = channel — empirically 52us;
//  the vectorized 4ch/thread rewrite regressed to 126us, reverted)
__global__ __launch_bounds__(256) void k_out_tile3(const unsigned short* __restrict__ h3b,
        const float* __restrict__ st3R, const float* __restrict__ g3,
        const float* __restrict__ b3g, float invn, const int* __restrict__ binv,
        float* __restrict__ out_fea, unsigned int* __restrict__ out_bev,
        const int* __restrict__ bcoords, float* __restrict__ out_vc, int Nb, int N) {
    int t = threadIdx.x, lane = t & 63, w = t >> 6;
    long gid = (long)blockIdx.x * 256 + t;
    if (gid < Nb) {
        int cc = bcoords[gid];
        int vb = cc / BEV_SXY;
        int rem = cc % BEV_SXY;
        int vx = rem / BEV_SY;
        int vy = rem % BEV_SY;
        out_vc[gid * 4 + 0] = (float)vb;
        out_vc[gid * 4 + 1] = 0.f;
        out_vc[gid * 4 + 2] = (float)vy;
        out_vc[gid * 4 + 3] = (float)vx;
    }
    int p = blockIdx.x * 4 + w;
    if (p >= N) return;
    float a, bb;
    bn_ab8(st3R, g3, b3g, 64, lane, invn, a, bb);
    float v = bnr(bf2f(h3b[(long)p * 64 + lane]), a, bb);
    out_fea[(long)p * 64 + lane] = v;
    int bi = binv[p];
    if (v > 0.f) {
        unsigned uv = __float_as_uint(v);
        unsigned* cell = out_bev + (long)bi * 64;
        unsigned cur = cell[lane];
        if (uv > cur) atomicMax(&cell[lane], uv);
    }
}

extern "C" void kernel_launch(void* const* d_in, const int* in_sizes, int n_in,
                              void* d_out, int out_size, void* d_ws, size_t ws_size,
                              hipStream_t stream) {
    const float* pts = (const float*)d_in[0];
    const float* pcyl = (const float*)d_in[1];
    const float* cylidx = (const float*)d_in[2];
    const float* bevidx = (const float*)d_in[3];
    const float* w1 = (const float*)d_in[4];
    const float* g1 = (const float*)d_in[5];
    const float* b1 = (const float*)d_in[6];
    const float* w2 = (const float*)d_in[7];
    const float* g2 = (const float*)d_in[8];
    const float* b2 = (const float*)d_in[9];
    const float* wc = (const float*)d_in[10];
    const float* gc = (const float*)d_in[11];
    const float* bc = (const float*)d_in[12];
    const float* w3 = (const float*)d_in[13];
    const float* g3 = (const float*)d_in[14];
    const float* b3 = (const float*)d_in[15];
    const int* binv = (const int*)d_in[16];
    const int* bcoords = (const int*)d_in[17];
    const int* cinv = (const int*)d_in[18];
    const int* ccoords = (const int*)d_in[19];
    int N = in_sizes[0] / 5;
    int Nb = in_sizes[17];
    int Nc = in_sizes[19];
    const int B = 4;
    const long GRIDSZ = (long)B * 512 * 48 * 64;
    float invN = 1.0f / (float)N;
    float invC = 1.0f / (float)(B * 512 * 48);

    // workspace layout: zero-init region (gridk..stats) is CONTIGUOUS -> one memset
    char* wsb = (char*)d_ws;
    unsigned short* wctb = (unsigned short*)wsb;                      // 73728 B
    unsigned short* h2b = (unsigned short*)(wsb + 73728);             // [N,64] bf16 (pointwise)
    unsigned short* h13b = (unsigned short*)(wsb + 73728 + 128L * N); // [N,64] bf16
    unsigned int* gridk = (unsigned int*)(wsb + 73728 + 256L * N);    // u32 max-keys
    unsigned long long* bacc = (unsigned long long*)(gridk + GRIDSZ); // 2*Nb u64
    unsigned long long* cacc = bacc + 2L * Nb;                        // 2*Nc u64
    float* stats = (float*)(cacc + 2L * Nc);                          // 5120 floats (8-way replicas)
    float* st1R = stats;               // 8 * 128
    float* st2R = stats + 1024;        // 8 * 256
    float* st3R = stats + 3072;        // 8 * 128
    float* stCR = stats + 4096;        // 8 * 128
    unsigned short* convb = (unsigned short*)(stats + 5120);          // bf16 conv output

    float* out_fea = (float*)d_out;
    unsigned int* out_bev = (unsigned int*)((float*)d_out + (long)N * 64);
    float* out_vc = (float*)d_out + (long)N * 64 + (long)Nb * 64;

    size_t zbytes = (size_t)GRIDSZ * 4 + (size_t)(2L * Nb + 2L * Nc) * 8 + 5120 * 4;
    hipMemsetAsync(gridk, 0, zbytes, stream);
    hipMemsetAsync(out_bev, 0, (size_t)Nb * 64 * 4, stream);

    int nb256 = (N + 255) / 256;
    k_scatter_sums<<<nb256, 256, 0, stream>>>(pts, pcyl, binv, cinv, wc, wctb, bacc, cacc, N, Nb, Nc);
    k_feat_gemm1<<<nb256, 256, 0, stream>>>(pts, pcyl, cylidx, bevidx, binv, cinv, bacc, cacc, w1, h13b, st1R, N, Nb, Nc);
    k_gemm2_mfma<<<512, 256, 0, stream>>>(h13b, w2, st1R, g1, b1, invN, pts, cylidx, g2, gridk, h2b, st2R, N);
    k_conv_lds<<<1024, 768, 0, stream>>>(gridk, wctb, convb, st2R, g2, b2, invN, stCR);
    k_gather3_mfma<<<512, 256, 0, stream>>>(h2b, convb, st2R, g2, b2, stCR, gc, bc, invN, invC, cylidx, pts, w3, h13b, st3R, N);
    k_out_tile3<<<(N + 3) / 4, 256, 0, stream>>>(h13b, st3R, g3, b3, invN, binv, out_fea, out_bev, bcoords, out_vc, Nb, N);
}